// Round 1
// baseline (238.862 us; speedup 1.0000x reference)
//
#include <hip/hip_runtime.h>
#include <hip/hip_bf16.h>

// Embedding gather: out[b,s,:] = W_E[tokens[b,s],:]
// tokens: int32[32768], W_E: float32[50257,768], out: float32[32768,768]
//
// One 64-lane wave per 4 tokens. Each lane holds 12 float4 in flight
// (4 rows x 3 float4/lane) before storing -> 4x the memory-level
// parallelism of the wave-per-token version.
//
// R1 EXPERIMENT: plain cached stores instead of __builtin_nontemporal_store.
// Rationale: timed replay loop (237 us) is 2.5x SLOWER than the cold
// isolated rocprof dispatch (<95 us), the opposite of what the "NT keeps
// W_E LLC-resident" theory predicts. The harness's fill kernels prove
// plain stores sustain 6.4 TB/s on this chip; the nt drain path is the
// prime suspect for the gap. Single-variable A/B: stores only.

typedef float v4f __attribute__((ext_vector_type(4)));

#define ROW4 192  // 768 floats / 4 = float4 per embedding row

__global__ __launch_bounds__(256) void embed_gather_kernel(
    const int* __restrict__ tokens,
    const v4f* __restrict__ W_E,
    v4f* __restrict__ out,
    int n_tokens)
{
    const int gtid = blockIdx.x * blockDim.x + threadIdx.x;
    const int wave = gtid >> 6;
    const int lane = threadIdx.x & 63;
    const int tok_base = wave * 4;
    if (tok_base >= n_tokens) return;

    if (tok_base + 4 <= n_tokens) {
        // Fast path: 4 tokens per wave, fully unrolled.
        const int4 t4 = *(const int4*)(tokens + tok_base);

        const v4f* __restrict__ s0 = W_E + (size_t)t4.x * ROW4;
        const v4f* __restrict__ s1 = W_E + (size_t)t4.y * ROW4;
        const v4f* __restrict__ s2 = W_E + (size_t)t4.z * ROW4;
        const v4f* __restrict__ s3 = W_E + (size_t)t4.w * ROW4;
        v4f* __restrict__ d = out + (size_t)tok_base * ROW4;

        v4f r[12];
        #pragma unroll
        for (int i = 0; i < 3; ++i) {
            const int idx = lane + i * 64;
            r[i]     = s0[idx];
            r[3 + i] = s1[idx];
            r[6 + i] = s2[idx];
            r[9 + i] = s3[idx];
        }
        #pragma unroll
        for (int i = 0; i < 3; ++i) {
            const int idx = lane + i * 64;
            d[idx]            = r[i];
            d[ROW4 + idx]     = r[3 + i];
            d[2 * ROW4 + idx] = r[6 + i];
            d[3 * ROW4 + idx] = r[9 + i];
        }
    } else {
        // Tail: per-token copy (not hit for n_tokens % 4 == 0).
        for (int t = tok_base; t < n_tokens; ++t) {
            const int tok = tokens[t];
            const v4f* __restrict__ src = W_E + (size_t)tok * ROW4;
            v4f* __restrict__ dst = out + (size_t)t * ROW4;
            #pragma unroll
            for (int i = 0; i < 3; ++i) {
                const int idx = lane + i * 64;
                dst[idx] = src[idx];
            }
        }
    }
}

extern "C" void kernel_launch(void* const* d_in, const int* in_sizes, int n_in,
                              void* d_out, int out_size, void* d_ws, size_t ws_size,
                              hipStream_t stream)
{
    const int* tokens = (const int*)d_in[0];
    const v4f* W_E    = (const v4f*)d_in[1];
    v4f*       out    = (v4f*)d_out;

    const int n_tokens = in_sizes[0];  // 8 * 4096 = 32768

    // 4 tokens per wave, 4 waves per 256-thread block -> 16 tokens/block.
    const int n_waves = (n_tokens + 3) / 4;
    const int blocks  = (n_waves + 3) / 4;
    embed_gather_kernel<<<blocks, 256, 0, stream>>>(
        tokens, W_E, out, n_tokens);
}

// Round 2
// 229.952 us; speedup vs baseline: 1.0387x; 1.0387x over previous
//
#include <hip/hip_runtime.h>
#include <hip/hip_bf16.h>

// Embedding gather: out[b,s,:] = W_E[tokens[b,s],:]
// tokens: int32[32768], W_E: float32[50257,768], out: float32[32768,768]
//
// One 64-lane wave per 4 tokens. Each lane holds 12 float4 in flight
// (4 rows x 3 float4/lane) before storing -> 4x the memory-level
// parallelism of the wave-per-token version.
//
// R2 EXPERIMENT: non-temporal LOADS for W_E (+ nt stores, = R0 baseline
// on the store side, which R1 proved perf-neutral).
// Theory: the harness's 617 MB re-poison fill runs immediately before the
// kernel in the timed graph, leaving the 256 MB LLC full of dirty lines.
// Cache-allocating reads (100 MB) + stores (100 MB) then force dirty-line
// writebacks during OUR kernel -> up to ~256 MB extra HBM write traffic.
// nt loads skip LLC allocation on the read stream, eliminating the larger
// half of that tax. Predicted dur_us 237 -> ~200-215 if theory holds;
// unchanged => kernel memory path exhausted (all 4 nt/plain combos null).

typedef float v4f __attribute__((ext_vector_type(4)));

#define ROW4 192  // 768 floats / 4 = float4 per embedding row

__global__ __launch_bounds__(256) void embed_gather_kernel(
    const int* __restrict__ tokens,
    const v4f* __restrict__ W_E,
    v4f* __restrict__ out,
    int n_tokens)
{
    const int gtid = blockIdx.x * blockDim.x + threadIdx.x;
    const int wave = gtid >> 6;
    const int lane = threadIdx.x & 63;
    const int tok_base = wave * 4;
    if (tok_base >= n_tokens) return;

    if (tok_base + 4 <= n_tokens) {
        // Fast path: 4 tokens per wave, fully unrolled.
        const int4 t4 = *(const int4*)(tokens + tok_base);

        const v4f* __restrict__ s0 = W_E + (size_t)t4.x * ROW4;
        const v4f* __restrict__ s1 = W_E + (size_t)t4.y * ROW4;
        const v4f* __restrict__ s2 = W_E + (size_t)t4.z * ROW4;
        const v4f* __restrict__ s3 = W_E + (size_t)t4.w * ROW4;
        v4f* __restrict__ d = out + (size_t)tok_base * ROW4;

        v4f r[12];
        #pragma unroll
        for (int i = 0; i < 3; ++i) {
            const int idx = lane + i * 64;
            r[i]     = __builtin_nontemporal_load(s0 + idx);
            r[3 + i] = __builtin_nontemporal_load(s1 + idx);
            r[6 + i] = __builtin_nontemporal_load(s2 + idx);
            r[9 + i] = __builtin_nontemporal_load(s3 + idx);
        }
        #pragma unroll
        for (int i = 0; i < 3; ++i) {
            const int idx = lane + i * 64;
            __builtin_nontemporal_store(r[i],     d + idx);
            __builtin_nontemporal_store(r[3 + i], d + ROW4     + idx);
            __builtin_nontemporal_store(r[6 + i], d + 2 * ROW4 + idx);
            __builtin_nontemporal_store(r[9 + i], d + 3 * ROW4 + idx);
        }
    } else {
        // Tail: per-token copy (not hit for n_tokens % 4 == 0).
        for (int t = tok_base; t < n_tokens; ++t) {
            const int tok = tokens[t];
            const v4f* __restrict__ src = W_E + (size_t)tok * ROW4;
            v4f* __restrict__ dst = out + (size_t)t * ROW4;
            #pragma unroll
            for (int i = 0; i < 3; ++i) {
                const int idx = lane + i * 64;
                __builtin_nontemporal_store(
                    __builtin_nontemporal_load(src + idx), dst + idx);
            }
        }
    }
}

extern "C" void kernel_launch(void* const* d_in, const int* in_sizes, int n_in,
                              void* d_out, int out_size, void* d_ws, size_t ws_size,
                              hipStream_t stream)
{
    const int* tokens = (const int*)d_in[0];
    const v4f* W_E    = (const v4f*)d_in[1];
    v4f*       out    = (v4f*)d_out;

    const int n_tokens = in_sizes[0];  // 8 * 4096 = 32768

    // 4 tokens per wave, 4 waves per 256-thread block -> 16 tokens/block.
    const int n_waves = (n_tokens + 3) / 4;
    const int blocks  = (n_waves + 3) / 4;
    embed_gather_kernel<<<blocks, 256, 0, stream>>>(
        tokens, W_E, out, n_tokens);
}

// Round 3
// 229.690 us; speedup vs baseline: 1.0399x; 1.0011x over previous
//
#include <hip/hip_runtime.h>
#include <hip/hip_bf16.h>

// Embedding gather: out[b,s,:] = W_E[tokens[b,s],:]
// tokens: int32[32768], W_E: float32[50257,768], out: float32[32768,768]
//
// R3 EXPERIMENT: 2 tokens/wave (was 4) to cut VGPRs ~70 -> ~40.
// Occupancy steps at VGPR=64 on gfx950 (waves/SIMD: 8 -> 4 above 64).
// Evidence this kernel is latency- not BW-bound: store-policy change
// (±100 MB implied LLC-writeback traffic) moved dur_us <1%, while
// nt LOADS (shorter miss path: no LLC victim eviction) bought 9 us.
// 2 tok/wave keeps per-CU in-flight bytes identical (32 waves x 6 KB
// vs 16 x 12 KB) but doubles independent request streams and makes the
// grid 2 generations (4096 blocks vs all-resident 2048) so fresh waves'
// loads overlap retiring waves' store drains.
// Keep R2's nt loads + nt stores (best measured combo: 230.0 us).
// Predict dur 230 -> <=215 if occupancy was limiting; unchanged => kernel
// at its ~35 us roofline and the floor is the harness's 94 us fill +
// small-op overhead (fill IDs are ==4 mod 5: exactly one per iteration).

typedef float v4f __attribute__((ext_vector_type(4)));

#define ROW4 192  // 768 floats / 4 = float4 per embedding row

__global__ __launch_bounds__(256) void embed_gather_kernel(
    const int* __restrict__ tokens,
    const v4f* __restrict__ W_E,
    v4f* __restrict__ out,
    int n_tokens)
{
    const int gtid = blockIdx.x * blockDim.x + threadIdx.x;
    const int wave = gtid >> 6;
    const int lane = threadIdx.x & 63;
    const int tok_base = wave * 2;
    if (tok_base >= n_tokens) return;

    if (tok_base + 2 <= n_tokens) {
        // Fast path: 2 tokens per wave, fully unrolled.
        const int2 t2 = *(const int2*)(tokens + tok_base);

        const v4f* __restrict__ s0 = W_E + (size_t)t2.x * ROW4;
        const v4f* __restrict__ s1 = W_E + (size_t)t2.y * ROW4;
        v4f* __restrict__ d = out + (size_t)tok_base * ROW4;

        v4f r[6];
        #pragma unroll
        for (int i = 0; i < 3; ++i) {
            const int idx = lane + i * 64;
            r[i]     = __builtin_nontemporal_load(s0 + idx);
            r[3 + i] = __builtin_nontemporal_load(s1 + idx);
        }
        #pragma unroll
        for (int i = 0; i < 3; ++i) {
            const int idx = lane + i * 64;
            __builtin_nontemporal_store(r[i],     d + idx);
            __builtin_nontemporal_store(r[3 + i], d + ROW4 + idx);
        }
    } else {
        // Tail: per-token copy (not hit for n_tokens % 2 == 0).
        for (int t = tok_base; t < n_tokens; ++t) {
            const int tok = tokens[t];
            const v4f* __restrict__ src = W_E + (size_t)tok * ROW4;
            v4f* __restrict__ dst = out + (size_t)t * ROW4;
            #pragma unroll
            for (int i = 0; i < 3; ++i) {
                const int idx = lane + i * 64;
                __builtin_nontemporal_store(
                    __builtin_nontemporal_load(src + idx), dst + idx);
            }
        }
    }
}

extern "C" void kernel_launch(void* const* d_in, const int* in_sizes, int n_in,
                              void* d_out, int out_size, void* d_ws, size_t ws_size,
                              hipStream_t stream)
{
    const int* tokens = (const int*)d_in[0];
    const v4f* W_E    = (const v4f*)d_in[1];
    v4f*       out    = (v4f*)d_out;

    const int n_tokens = in_sizes[0];  // 8 * 4096 = 32768

    // 2 tokens per wave, 4 waves per 256-thread block -> 8 tokens/block.
    const int n_waves = (n_tokens + 1) / 2;
    const int blocks  = (n_waves + 3) / 4;
    embed_gather_kernel<<<blocks, 256, 0, stream>>>(
        tokens, W_E, out, n_tokens);
}